// Round 1
// baseline (329.176 us; speedup 1.0000x reference)
//
#include <hip/hip_runtime.h>
#include <hip/hip_bf16.h>
#include <stdint.h>

// MutualCrossAttention: B=8, C=64, H=W=64 -> T=4096 tokens. Inputs FP32, output FP32.
// dir A: Q=x1, K=V=x2 ; dir B: Q=x2, K=V=x1 ; out = outA + outB, layout [b][c][t].
// R13: barrier-free main loop. The staged-ktile K-fragment read pattern is identical
// to a direct global token-major read, and the whole working set (4 MB/batch) is
// L2-resident with b = blockIdx.x & 7 matching the XCD round-robin. So K frags are
// loaded straight from xt (prefetched one j ahead, covered by the PV phase), the
// staging role + both per-j __syncthreads are deleted, and all 8 waves free-run
// until the epilogue merge. pbuf (P^T round-trip) stays wave-private in LDS:
//   - S^T composition (A=K,B=Q then A=V,B=P^T): P^T C/D gives 4 consecutive
//     tokens/lane -> b64 write, b128 read, stride-72 rows at bank minimum.
//   - lp is one scalar per lane (q = l16 column), butterflied over quads.
//   - O^T epilogue: row=c, col=q -> scalar f32 stores coalesced over l16.
// ws: [0,8MB) xt bf16 token-major {x1,x2} PRE-SCALED by sqrt(log2(e)/8);
//     [8MB,16MB) vt bf16 c-major {x1,x2} unscaled.

#define TT 4096
#define CC 64
#define NB 8

typedef float f32x4 __attribute__((ext_vector_type(4)));
typedef float f32x4a __attribute__((ext_vector_type(4), may_alias));
typedef short s16x8 __attribute__((ext_vector_type(8)));
typedef unsigned int u32x2a __attribute__((ext_vector_type(2), may_alias));
typedef unsigned int u32x4a __attribute__((ext_vector_type(4), may_alias));
typedef float f32a __attribute__((may_alias));

static __device__ __forceinline__ unsigned fbits(float x) { return __float_as_uint(x); }
static __device__ __forceinline__ ushort bf16of(float v) {
    return (ushort)((fbits(v) + 0x8000u) >> 16);
}
static __device__ __forceinline__ unsigned pack2(float a, float b) {
    return __builtin_amdgcn_perm(fbits(b) + 0x8000u, fbits(a) + 0x8000u, 0x07060302u);
}
static __device__ __forceinline__ s16x8 load_frag(const void* p) {
    u32x4a t = *(const u32x4a*)p;
    return __builtin_bit_cast(s16x8, t);
}

#define SQC1 0.4246609177f  // sqrt(log2(e)/8), applied to xt on both Q and K sides

__global__ void prep_k(const float* __restrict__ x1, const float* __restrict__ x2,
                       ushort* __restrict__ xt, ushort* __restrict__ vt) {
    const int inp = blockIdx.z, b = blockIdx.y, t0 = blockIdx.x * 64;
    const float* src = (inp == 0 ? x1 : x2) + (size_t)b * CC * TT;
    const size_t plane = (size_t)TT * CC;
    ushort* xd = xt + (size_t)(inp * NB + b) * plane;
    ushort* vd = vt + (size_t)(inp * NB + b) * plane;
    __shared__ ushort lds[64][72];
    const int tid = threadIdx.x;
    const int c  = tid >> 2;
    const int tg = tid & 3;
    const float* srow = src + (size_t)c * TT + t0 + tg * 16;
    unsigned hw[8];
#pragma unroll
    for (int i = 0; i < 4; ++i) {
        f32x4a v = *(const f32x4a*)(srow + i * 4);
        hw[2 * i]     = pack2(v[0], v[1]);
        hw[2 * i + 1] = pack2(v[2], v[3]);
#pragma unroll
        for (int k = 0; k < 4; ++k) lds[tg * 16 + i * 4 + k][c] = bf16of(v[k] * SQC1);
    }
    ushort* vrow = vd + (size_t)c * TT + t0 + tg * 16;
    u32x4a w0 = {hw[0], hw[1], hw[2], hw[3]};
    u32x4a w1 = {hw[4], hw[5], hw[6], hw[7]};
    *(u32x4a*)(vrow) = w0;
    *(u32x4a*)(vrow + 8) = w1;
    __syncthreads();
#pragma unroll
    for (int pass = 0; pass < 2; ++pass) {
        const int t  = (tid >> 3) + pass * 32;
        const int c8 = (tid & 7) * 8;
        u32x4a w = *(const u32x4a*)&lds[t][c8];
        *(u32x4a*)(xd + (size_t)(t0 + t) * CC + c8) = w;
    }
}

// grid = 512 blocks (qt 0..63 x b 0..7), 512 threads = 8 waves.
// wave: dir = w&1, pair = (w>>1)&1, ks = w>>2 (2048-token half).
__global__ __launch_bounds__(512, 4)
void attn_fused_k(const ushort* __restrict__ xt, const ushort* __restrict__ vt,
                  float* __restrict__ out) {
    const int b    = blockIdx.x & 7;
    const int qt   = blockIdx.x >> 3;
    const int tid  = threadIdx.x;
    const int wave = tid >> 6;
    const int lane = tid & 63;
    const int quad = lane >> 4;
    const int l16  = lane & 15;
    const int dir  = wave & 1;
    const int pair = (wave >> 1) & 1;
    const int ks   = wave >> 2;
    const int q0   = qt * 64 + pair * 32;

    const size_t plane = (size_t)TT * CC;
    const ushort* Qb = xt + (size_t)((dir == 0 ? 0 : NB) + b) * plane;  // token-major
    const ushort* Kb = xt + (size_t)((dir == 0 ? NB : 0) + b) * plane;  // token-major
    const ushort* Vb = vt + (size_t)((dir == 0 ? NB : 0) + b) * plane;  // c-major

    __shared__ __align__(16) ushort pbuf[8][2][16][72];    // 36.9 KB (q rows, tok cols)
    __shared__ float lpx[8][2][16];                        // 1 KB
    f32a* xbuf = (f32a*)&pbuf[0][0][0][0];                 // 16 KB overlay, post-loop

    // Q b-frags: B[n=q=l16][k=c=quad*8+j], pre-scaled.
    s16x8 qf[2][2];
#pragma unroll
    for (int rb = 0; rb < 2; ++rb)
#pragma unroll
        for (int ch = 0; ch < 2; ++ch)
            qf[rb][ch] = load_frag(Qb + (size_t)(q0 + rb * 16 + l16) * CC + ch * 32 + quad * 8);

    f32x4 accO[2][4];  // O^T partial: row=c=quad*4+r (+ct*16), col=q=l16 (+rb*16)
#pragma unroll
    for (int rb = 0; rb < 2; ++rb)
#pragma unroll
        for (int ct = 0; ct < 4; ++ct) accO[rb][ct] = (f32x4){0.f, 0.f, 0.f, 0.f};
    float lp[2] = {0.f, 0.f};

    // Direct-global K frags: A[m=tok=mt*16+l16][k=c=quad*8..], token-major xt row.
    const ushort* kbase = Kb + (size_t)(ks * 2048 + l16) * CC + quad * 8;
    const ushort* vbase = Vb + (size_t)l16 * TT + ks * 2048 + quad * 8;

    s16x8 kf[4][2];
    auto loadK = [&](int j) {
        const ushort* kp = kbase + (size_t)j * 64 * CC;
#pragma unroll
        for (int mt = 0; mt < 4; ++mt) {
            kf[mt][0] = load_frag(kp + mt * 16 * CC);
            kf[mt][1] = load_frag(kp + mt * 16 * CC + 32);
        }
    };

    // S^T(j): A = K frag (registers), B = Q.
    // D[row=tok=quad*4+r (+mt*16)][col=q=l16] -> 4 consecutive tokens -> b64 P write.
    auto Sphase = [&]() {
#pragma unroll
        for (int mt = 0; mt < 4; ++mt) {
#pragma unroll
            for (int rb = 0; rb < 2; ++rb) {
                f32x4 s = (f32x4){0.f, 0.f, 0.f, 0.f};
                s = __builtin_amdgcn_mfma_f32_16x16x32_bf16(kf[mt][0], qf[rb][0], s, 0, 0, 0);
                s = __builtin_amdgcn_mfma_f32_16x16x32_bf16(kf[mt][1], qf[rb][1], s, 0, 0, 0);
                float p0 = __builtin_amdgcn_exp2f(s[0]);
                float p1 = __builtin_amdgcn_exp2f(s[1]);
                float p2 = __builtin_amdgcn_exp2f(s[2]);
                float p3 = __builtin_amdgcn_exp2f(s[3]);
                lp[rb] += (p0 + p1) + (p2 + p3);
                u32x2a w;
                w[0] = pack2(p0, p1);
                w[1] = pack2(p2, p3);
                *(u32x2a*)&pbuf[wave][rb][l16][mt * 16 + quad * 4] = w;
            }
        }
    };
    // PV(j): A = V [m=c=l16(+ct*16)][k=tok], B = P^T [n=q=l16][k=tok] (b128 LDS).
    auto PVphase = [&](int j) {
        const int k0 = j * 64;
#pragma unroll
        for (int ch2 = 0; ch2 < 2; ++ch2) {
            s16x8 pf[2];
#pragma unroll
            for (int rb = 0; rb < 2; ++rb)
                pf[rb] = load_frag(&pbuf[wave][rb][l16][ch2 * 32 + quad * 8]);
#pragma unroll
            for (int ct = 0; ct < 4; ++ct) {
                s16x8 vf = load_frag(vbase + (size_t)(ct * 16) * TT + k0 + ch2 * 32);
#pragma unroll
                for (int rb = 0; rb < 2; ++rb)
                    accO[rb][ct] = __builtin_amdgcn_mfma_f32_16x16x32_bf16(
                        vf, pf[rb], accO[rb][ct], 0, 0, 0);
            }
        }
    };

    // Barrier-free pipeline: kf(j+1) issued between S(j) and PV(j) so the K loads
    // are covered by the PV phase; pbuf is wave-private (in-order DS per wave).
    loadK(0);
#pragma unroll 1
    for (int j = 0; j < 32; ++j) {
        Sphase();
        if (j < 31) loadK(j + 1);
        PVphase(j);
    }

    // Denominator: quads hold disjoint token subsets for col q=l16.
    float inv[2];
#pragma unroll
    for (int rb = 0; rb < 2; ++rb) {
        float l = lp[rb];
        l += __shfl_xor(l, 16);
        l += __shfl_xor(l, 32);
        lp[rb] = l;
        if (lane < 16) lpx[wave][rb][l16] = l;
    }
    __syncthreads();  // all waves done with pbuf -> xbuf overlay safe; lpx visible
#pragma unroll
    for (int rb = 0; rb < 2; ++rb)
        inv[rb] = __builtin_amdgcn_rcpf(lp[rb] + lpx[wave ^ 4][rb][l16]);

    // 4-phase merge over g = (ks,dir) into xbuf[pair]; g==0 stores.
    const int g = (ks << 1) | dir;
#pragma unroll 1
    for (int ph = 3; ph >= 1; --ph) {
        if (g == ph) {
#pragma unroll
            for (int rb = 0; rb < 2; ++rb)
#pragma unroll
                for (int ct = 0; ct < 4; ++ct)
#pragma unroll
                    for (int r = 0; r < 4; ++r) {
                        const int slot = (pair * 32 + rb * 16 + ct * 4 + r) * 64 + lane;
                        float v = accO[rb][ct][r] * inv[rb];
                        if (ph == 3) xbuf[slot] = v;
                        else xbuf[slot] += v;
                    }
        }
        __syncthreads();
    }
    if (g == 0) {
        float* ob = out + (size_t)b * plane;
#pragma unroll
        for (int rb = 0; rb < 2; ++rb)
#pragma unroll
            for (int ct = 0; ct < 4; ++ct)
#pragma unroll
                for (int r = 0; r < 4; ++r) {
                    float v = accO[rb][ct][r] * inv[rb] +
                              xbuf[(pair * 32 + rb * 16 + ct * 4 + r) * 64 + lane];
                    // out[c = ct*16+quad*4+r][t = q0+rb*16+l16]: coalesced over l16
                    ob[(size_t)(ct * 16 + quad * 4 + r) * TT + q0 + rb * 16 + l16] = v;
                }
    }
}

extern "C" void kernel_launch(void* const* d_in, const int* in_sizes, int n_in,
                              void* d_out, int out_size, void* d_ws, size_t ws_size,
                              hipStream_t stream) {
    const float* x1 = (const float*)d_in[0];
    const float* x2 = (const float*)d_in[1];
    ushort* xt = (ushort*)d_ws;                              // 8 MB
    ushort* vt = (ushort*)d_ws + (size_t)2 * NB * TT * CC;   // 8 MB

    hipLaunchKernelGGL(prep_k, dim3(TT / 64, NB, 2), dim3(256), 0, stream, x1, x2, xt, vt);
    hipLaunchKernelGGL(attn_fused_k, dim3(64 * NB), dim3(512), 0, stream,
                       xt, vt, (float*)d_out);
}